// Round 13
// baseline (103.974 us; speedup 1.0000x reference)
//
#include <hip/hip_runtime.h>

// SmoothL1 + IoU-matching loss (levels [6400,1600,400], B=8, T=64, 9 groups).
// pred_i layout: (B, 36, L), element (b, a*4+c, l). target: (B, 64, 4).
//
// R11 changes vs R10 (kernel ~33us, e2e 93.6; fixed ~60us is harness d_ws
// poison fill, untouchable):
//  - Flat global anchor index [0, 604800): kills R10's 22% padding waste
//    (chunk rounding). 4-anchor groups never straddle ba/level boundaries
//    (6400, 8000, 8400 all % 4 == 0). Blocks cover contiguous 512-anchor
//    spans; stage ALL 8 batches' targets in LDS (10 KB) since a block can
//    cross one (b,a) boundary. Boundary waves read 2 LDS addresses 1 KB
//    apart = same bank, 2-way = free (m136).
//  - Cancelled-inter compare: iou_t > iou_b  <=>  inter_t*S_b > inter_b*S_t
//    with S = ap + (at+eps) (the inter_t*inter_b terms cancel exactly).
//    d = fmaxf(S, 1e-6): exact identity when inter>0 (S >= at+eps >= 1e-6);
//    any positive value when inter==0 (numerator 0: never steals from
//    nb>=0 best, and t=0 still taken unconditionally vs nb=-1 init).
//    Same <=1-ulp tie class as the R9/R10-validated cross-mult (absmax 0.0).
//  - at+eps folded into the staged per-target area.
//  - pos test in epilogue: nb > 0.5*(db-nb), 0.5*x exact, db>0 invariant.
//  - Separate 1-thread finalize kernel (R9 lesson: fused fence serializes).

#define NT     64
#define BLK    128
#define APT    4
#define SPAN   (BLK * APT)                 // 512 anchors per block
#define PER_BA 8400
#define TOTAL  (8 * 9 * PER_BA)            // 604800 anchors
#define NBLK   ((TOTAL + SPAN - 1) / SPAN) // 1182 blocks
#define L0     6400
#define L1     1600
#define L2     400

__global__ __launch_bounds__(BLK) void anchor_loss_kernel(
    const float* __restrict__ pred0,
    const float* __restrict__ pred1,
    const float* __restrict__ pred2,
    const float* __restrict__ target,   // 8*64*4 floats
    float* __restrict__ g_loss,
    int*   __restrict__ g_cnt)
{
    // Stage all 8 batches' targets: box float4 + (area+eps).
    __shared__ float4 tbox[8 * NT];
    __shared__ float  tat [8 * NT];
    const int tid = threadIdx.x;
    #pragma unroll
    for (int i = 0; i < (8 * NT) / BLK; ++i)        // 4 coalesced rounds
        tbox[i * BLK + tid] = ((const float4*)target)[i * BLK + tid];
    __syncthreads();
    #pragma unroll
    for (int i = 0; i < (8 * NT) / BLK; ++i) {
        const float4 t4 = tbox[i * BLK + tid];
        tat[i * BLK + tid] = (t4.z - t4.x) * (t4.w - t4.y) + 1e-6f;
    }
    __syncthreads();

    // Flat anchor index -> (b, a, level, l). Constant divisors: magic-mul.
    const int  g0    = blockIdx.x * SPAN + tid * APT;
    const bool valid = (g0 < TOTAL);
    const int  gc    = valid ? g0 : 0;      // clamp: safe in-bounds addresses
    const int  ba    = gc / PER_BA;
    const int  r     = gc - ba * PER_BA;
    const int  b     = ba / 9;
    const int  a     = ba - b * 9;

    const float* pred; int L; int l;
    if (r < L0)           { pred = pred0; L = L0; l = r; }
    else if (r < L0 + L1) { pred = pred1; L = L1; l = r - L0; }
    else                  { pred = pred2; L = L2; l = r - (L0 + L1); }

    const size_t base = ((size_t)b * 36 + (size_t)a * 4) * (size_t)L + (size_t)l;
    const float4 r0 = *(const float4*)(pred + base);
    const float4 r1 = *(const float4*)(pred + base + (size_t)L);
    const float4 r2 = *(const float4*)(pred + base + 2 * (size_t)L);
    const float4 r3 = *(const float4*)(pred + base + 3 * (size_t)L);

    float p0[APT] = {r0.x, r0.y, r0.z, r0.w};
    float p1[APT] = {r1.x, r1.y, r1.z, r1.w};
    float p2[APT] = {r2.x, r2.y, r2.z, r2.w};
    float p3[APT] = {r3.x, r3.y, r3.z, r3.w};

    float ap[APT], nb[APT], db[APT];
    int   bi[APT];
    #pragma unroll
    for (int j = 0; j < APT; ++j) {
        ap[j] = (p2[j] - p0[j]) * (p3[j] - p1[j]);
        nb[j] = -1.0f;   // t=0 always taken (rhs = -d < 0 <= inter)
        db[j] = 1.0f;
        bi[j] = 0;
    }

    const int tb_base = b * NT;
    #pragma unroll 4
    for (int t = 0; t < NT; ++t) {
        const float4 tb = tbox[tb_base + t];   // ds_read_b128 (broadcast/2-way)
        const float  at = tat [tb_base + t];   // ds_read_b32
        #pragma unroll
        for (int j = 0; j < APT; ++j) {
            const float x1 = fmaxf(p0[j], tb.x);
            const float y1 = fmaxf(p1[j], tb.y);
            const float x2 = fminf(p2[j], tb.z);
            const float y2 = fminf(p3[j], tb.w);
            const float iw = fmaxf(x2 - x1, 0.0f);
            const float ih = fmaxf(y2 - y1, 0.0f);
            const float inter = iw * ih;
            const float S = ap[j] + at;            // ap + (at+eps)
            const float d = fmaxf(S, 1e-6f);       // >0; == S when inter>0
            // iou_t > best  <=>  inter*db > nb*d  (inter_t*inter_b cancels)
            if (inter * db[j] > nb[j] * d) {
                nb[j] = inter; db[j] = d; bi[j] = t;
            }
        }
    }

    float lloss = 0.0f;
    int   lpos  = 0;
    if (valid) {
        #pragma unroll
        for (int j = 0; j < APT; ++j) {
            // best_iou > 0.5  <=>  nb > 0.5*(db - nb)   (denom recovered)
            const float denom = db[j] - nb[j];
            if (nb[j] > 0.5f * denom) {
                const float4 tb = tbox[tb_base + bi[j]];
                float s = 0.0f;
                { float d = p0[j] - tb.x, ad = fabsf(d); s += (ad < 1.0f) ? 0.5f * ad * ad : ad - 0.5f; }
                { float d = p1[j] - tb.y, ad = fabsf(d); s += (ad < 1.0f) ? 0.5f * ad * ad : ad - 0.5f; }
                { float d = p2[j] - tb.z, ad = fabsf(d); s += (ad < 1.0f) ? 0.5f * ad * ad : ad - 0.5f; }
                { float d = p3[j] - tb.w, ad = fabsf(d); s += (ad < 1.0f) ? 0.5f * ad * ad : ad - 0.5f; }
                lloss += s;
                lpos  += 1;
            }
        }
    }

    // wave(64) shuffle reduce, cross-wave via LDS, one atomic pair per block
    #pragma unroll
    for (int off = 32; off > 0; off >>= 1) {
        lloss += __shfl_down(lloss, off);
        lpos  += __shfl_down(lpos,  off);
    }
    __shared__ float wl[BLK / 64];
    __shared__ int   wc[BLK / 64];
    const int wave = tid >> 6;
    if ((tid & 63) == 0) { wl[wave] = lloss; wc[wave] = lpos; }
    __syncthreads();
    if (tid == 0) {
        float s = 0.0f; int c = 0;
        #pragma unroll
        for (int w = 0; w < BLK / 64; ++w) { s += wl[w]; c += wc[w]; }
        atomicAdd(g_loss, s);
        atomicAdd(g_cnt, c);
    }
}

__global__ void finalize_kernel(const float* __restrict__ g_loss,
                                const int*   __restrict__ g_cnt,
                                float* __restrict__ out)
{
    const int n = *g_cnt;
    out[0] = (*g_loss) / (float)(n > 0 ? n : 1);
}

extern "C" void kernel_launch(void* const* d_in, const int* in_sizes, int n_in,
                              void* d_out, int out_size, void* d_ws, size_t ws_size,
                              hipStream_t stream)
{
    (void)in_sizes; (void)n_in; (void)out_size; (void)ws_size;
    const float* pred0  = (const float*)d_in[0];
    const float* pred1  = (const float*)d_in[1];
    const float* pred2  = (const float*)d_in[2];
    const float* target = (const float*)d_in[3];

    float* g_loss = (float*)d_ws;
    int*   g_cnt  = (int*)((char*)d_ws + sizeof(float));

    // d_ws is re-poisoned 0xAA before every timed launch -> zero accumulators.
    hipMemsetAsync(d_ws, 0, 2 * sizeof(float), stream);

    anchor_loss_kernel<<<NBLK, BLK, 0, stream>>>(pred0, pred1, pred2, target,
                                                 g_loss, g_cnt);
    finalize_kernel<<<1, 1, 0, stream>>>(g_loss, g_cnt, (float*)d_out);
}

// Round 14
// 100.403 us; speedup vs baseline: 1.0356x; 1.0356x over previous
//
#include <hip/hip_runtime.h>

// SmoothL1 + IoU-matching loss (levels [6400,1600,400], B=8, T=64, 9 groups).
// pred_i layout: (B, 36, L), element (b, a*4+c, l). target: (B, 64, 4).
//
// R14 vs R13 (42.7us, VALU 37%): the R10->R13 comparison showed throughput
// ~ proportional to resident waves (latency-bound). So: maximize waves,
// minimize per-block overhead.
//  - APT=2 (float2 loads, 8B/lane sweet spot; 2 indep IoU chains/thread)
//    -> 2x threads vs APT=4 at the same anchor count.
//  - 2D grid: blockIdx.y = ba (b,a pair; uniform per block -> no per-thread
//    magic div, 1KB LDS staging of batch b only, uniform tbox[t] addrs),
//    blockIdx.x = 512-anchor chunk, ceil(8400/512)=17 chunks (3.6% pad).
//    Grid 1224 blocks x 4 waves = 4896 waves (~19/CU) vs R10's 2880.
//  - Inner loop numerics = R13 (HW-validated absmax 0.0): cancelled-inter
//    compare inter*db > nb*d with d=fmax(ap+(at+eps),1e-6); pos test
//    nb > 0.5*(db-nb) in epilogue.
//  - Separate 1-thread finalize kernel (R9 lesson: fused fence serializes).

#define NT     64
#define BLK    256
#define APT    2
#define SPAN   (BLK * APT)                  // 512 anchors per block
#define PER_BA 8400
#define NCHUNK ((PER_BA + SPAN - 1) / SPAN) // 17
#define L0     6400
#define L1     1600
#define L2     400

__global__ __launch_bounds__(BLK) void anchor_loss_kernel(
    const float* __restrict__ pred0,
    const float* __restrict__ pred1,
    const float* __restrict__ pred2,
    const float* __restrict__ target,   // 8*64*4 floats
    float* __restrict__ g_loss,
    int*   __restrict__ g_cnt)
{
    const int ba = blockIdx.y;          // uniform: 0..71
    const int b  = ba / 9;              // scalar div by constant
    const int a  = ba - b * 9;

    // Stage batch b's 64 targets: float4 box + (area+eps). 1 KB + 256 B.
    __shared__ float4 tbox[NT];
    __shared__ float  tat [NT];
    const int tid = threadIdx.x;
    if (tid < NT)
        tbox[tid] = ((const float4*)(target + (size_t)b * NT * 4))[tid];
    __syncthreads();
    if (tid < NT) {
        const float4 t4 = tbox[tid];
        tat[tid] = (t4.z - t4.x) * (t4.w - t4.y) + 1e-6f;
    }
    __syncthreads();

    // 2 contiguous anchors per thread within this ba's 8400.
    const int  r0i   = blockIdx.x * SPAN + tid * APT;   // 0..8703
    const bool valid = (r0i < PER_BA);
    const int  r     = valid ? r0i : 0;

    const float* pred; int L; int l;
    if (r < L0)           { pred = pred0; L = L0; l = r; }
    else if (r < L0 + L1) { pred = pred1; L = L1; l = r - L0; }
    else                  { pred = pred2; L = L2; l = r - (L0 + L1); }

    const size_t base = ((size_t)b * 36 + (size_t)a * 4) * (size_t)L + (size_t)l;
    const float2 q0 = *(const float2*)(pred + base);
    const float2 q1 = *(const float2*)(pred + base + (size_t)L);
    const float2 q2 = *(const float2*)(pred + base + 2 * (size_t)L);
    const float2 q3 = *(const float2*)(pred + base + 3 * (size_t)L);

    float p0[APT] = {q0.x, q0.y};
    float p1[APT] = {q1.x, q1.y};
    float p2[APT] = {q2.x, q2.y};
    float p3[APT] = {q3.x, q3.y};

    float ap[APT], nb[APT], db[APT];
    int   bi[APT];
    #pragma unroll
    for (int j = 0; j < APT; ++j) {
        ap[j] = (p2[j] - p0[j]) * (p3[j] - p1[j]);
        nb[j] = -1.0f;   // t=0 always taken (rhs = -d < 0 <= inter)
        db[j] = 1.0f;
        bi[j] = 0;
    }

    #pragma unroll 4
    for (int t = 0; t < NT; ++t) {
        const float4 tb = tbox[t];          // uniform addr -> broadcast
        const float  at = tat [t];
        #pragma unroll
        for (int j = 0; j < APT; ++j) {
            const float x1 = fmaxf(p0[j], tb.x);
            const float y1 = fmaxf(p1[j], tb.y);
            const float x2 = fminf(p2[j], tb.z);
            const float y2 = fminf(p3[j], tb.w);
            const float iw = fmaxf(x2 - x1, 0.0f);
            const float ih = fmaxf(y2 - y1, 0.0f);
            const float inter = iw * ih;
            const float S = ap[j] + at;            // ap + (at+eps)
            const float d = fmaxf(S, 1e-6f);       // >0; == S when inter>0
            // iou_t > best  <=>  inter*db > nb*d  (inter_t*inter_b cancels)
            if (inter * db[j] > nb[j] * d) {
                nb[j] = inter; db[j] = d; bi[j] = t;
            }
        }
    }

    float lloss = 0.0f;
    int   lpos  = 0;
    if (valid) {
        #pragma unroll
        for (int j = 0; j < APT; ++j) {
            // best_iou > 0.5  <=>  nb > 0.5*(db - nb)
            const float denom = db[j] - nb[j];
            if (nb[j] > 0.5f * denom) {
                const float4 tb = tbox[bi[j]];
                float s = 0.0f;
                { float d = p0[j] - tb.x, ad = fabsf(d); s += (ad < 1.0f) ? 0.5f * ad * ad : ad - 0.5f; }
                { float d = p1[j] - tb.y, ad = fabsf(d); s += (ad < 1.0f) ? 0.5f * ad * ad : ad - 0.5f; }
                { float d = p2[j] - tb.z, ad = fabsf(d); s += (ad < 1.0f) ? 0.5f * ad * ad : ad - 0.5f; }
                { float d = p3[j] - tb.w, ad = fabsf(d); s += (ad < 1.0f) ? 0.5f * ad * ad : ad - 0.5f; }
                lloss += s;
                lpos  += 1;
            }
        }
    }

    // wave(64) shuffle reduce, cross-wave via LDS, one atomic pair per block
    #pragma unroll
    for (int off = 32; off > 0; off >>= 1) {
        lloss += __shfl_down(lloss, off);
        lpos  += __shfl_down(lpos,  off);
    }
    __shared__ float wl[BLK / 64];
    __shared__ int   wc[BLK / 64];
    const int wave = tid >> 6;
    if ((tid & 63) == 0) { wl[wave] = lloss; wc[wave] = lpos; }
    __syncthreads();
    if (tid == 0) {
        float s = 0.0f; int c = 0;
        #pragma unroll
        for (int w = 0; w < BLK / 64; ++w) { s += wl[w]; c += wc[w]; }
        atomicAdd(g_loss, s);
        atomicAdd(g_cnt, c);
    }
}

__global__ void finalize_kernel(const float* __restrict__ g_loss,
                                const int*   __restrict__ g_cnt,
                                float* __restrict__ out)
{
    const int n = *g_cnt;
    out[0] = (*g_loss) / (float)(n > 0 ? n : 1);
}

extern "C" void kernel_launch(void* const* d_in, const int* in_sizes, int n_in,
                              void* d_out, int out_size, void* d_ws, size_t ws_size,
                              hipStream_t stream)
{
    (void)in_sizes; (void)n_in; (void)out_size; (void)ws_size;
    const float* pred0  = (const float*)d_in[0];
    const float* pred1  = (const float*)d_in[1];
    const float* pred2  = (const float*)d_in[2];
    const float* target = (const float*)d_in[3];

    float* g_loss = (float*)d_ws;
    int*   g_cnt  = (int*)((char*)d_ws + sizeof(float));

    // d_ws is re-poisoned 0xAA before every timed launch -> zero accumulators.
    hipMemsetAsync(d_ws, 0, 2 * sizeof(float), stream);

    dim3 grid(NCHUNK, 8 * 9);   // 17 x 72 = 1224 blocks x 4 waves = 4896 waves
    anchor_loss_kernel<<<grid, BLK, 0, stream>>>(pred0, pred1, pred2, target,
                                                 g_loss, g_cnt);
    finalize_kernel<<<1, 1, 0, stream>>>(g_loss, g_cnt, (float*)d_out);
}